// Round 2
// baseline (345.827 us; speedup 1.0000x reference)
//
#include <hip/hip_runtime.h>
#include <hip/hip_bf16.h>

#define NFEAT 1024
#define CELL_EMB 1024
#define DRUG_EMB 128
#define HID 200
#define NDOSES 9
#define N_MISSING 100
#define N_DRUGS 256
#define S 16

typedef __hip_bfloat16 bf16;

// Templated load: F32=true -> buffer holds float32; false -> bfloat16.
template <bool F32>
__device__ __forceinline__ float ld(const void* p, int i) {
    if (F32) return ((const float*)p)[i];
    return __bfloat162float(((const bf16*)p)[i]);
}

// ---------------- dtype sniff: genuine bf16 W1 (~0.02 scale) never has |x|>=8.
// fp32-backed data read as bf16 has random exponent bits in even halfwords.
__global__ void sniff_kernel(const unsigned short* __restrict__ w1bits,
                             int* __restrict__ flag) {
    if (threadIdx.x == 0 && blockIdx.x == 0) {
        int f = 0;
        for (int i = 0; i < 512; ++i) {
            unsigned int e = (w1bits[i] >> 7) & 0xFFu;
            if (e >= 130u) f = 1;  // |val| >= 8 impossible for real bf16 W1
        }
        *flag = f;
    }
}

// ---------------- P[c] = relu(cell_features[c] @ W1 + b1), c in [0,100)
template <bool F32>
__global__ __launch_bounds__(256) void present_kernel(const int* __restrict__ flag,
                                                      const void* __restrict__ cell_features,
                                                      const void* __restrict__ W1,
                                                      const void* __restrict__ b1,
                                                      float* __restrict__ P) {
    if (*flag != (int)F32) return;          // uniform, before any barrier
    __shared__ float feat[NFEAT];
    int c = blockIdx.x;   // 0..99
    int jb = blockIdx.y;  // 0..3
    for (int k = threadIdx.x; k < NFEAT; k += 256)
        feat[k] = ld<F32>(cell_features, c * NFEAT + k);
    __syncthreads();
    int j = jb * 256 + threadIdx.x;
    float acc = ld<F32>(b1, j);
    for (int k = 0; k < NFEAT; ++k)
        acc = fmaf(feat[k], ld<F32>(W1, k * CELL_EMB + j), acc);
    P[c * CELL_EMB + j] = fmaxf(acc, 0.f);
}

// ---------------- Cc[r] = l2norm(r<100 ? P[r] : missing_emb[r-100]) @ Wf1[:1024]
template <bool F32>
__global__ __launch_bounds__(256) void cc_kernel(const int* __restrict__ flag,
                                                 const float* __restrict__ P,
                                                 const void* __restrict__ missing_emb,
                                                 const void* __restrict__ Wf1,
                                                 float* __restrict__ Cc) {
    if (*flag != (int)F32) return;
    int r = blockIdx.x;  // 0..199
    __shared__ float x[CELL_EMB];
    __shared__ float red[4];
    if (r < N_MISSING) {
        for (int k = threadIdx.x; k < CELL_EMB; k += 256) x[k] = P[r * CELL_EMB + k];
    } else {
        for (int k = threadIdx.x; k < CELL_EMB; k += 256)
            x[k] = ld<F32>(missing_emb, (r - N_MISSING) * CELL_EMB + k);
    }
    __syncthreads();
    float ss = 0.f;
    for (int k = threadIdx.x; k < CELL_EMB; k += 256) ss += x[k] * x[k];
    for (int o = 32; o > 0; o >>= 1) ss += __shfl_down(ss, o, 64);
    if ((threadIdx.x & 63) == 0) red[threadIdx.x >> 6] = ss;
    __syncthreads();
    float inv = 1.f / fmaxf(sqrtf(red[0] + red[1] + red[2] + red[3]), 1e-12f);
    int j = threadIdx.x;
    if (j < HID) {
        float acc = 0.f;
        for (int k = 0; k < CELL_EMB; ++k)
            acc = fmaf(x[k], ld<F32>(Wf1, k * HID + j), acc);
        Cc[r * HID + j] = acc * inv;
    }
}

// ---------------- Dc[d] = l2norm(drug_emb[d]) @ Wf1[1024:]
template <bool F32>
__global__ __launch_bounds__(256) void dc_kernel(const int* __restrict__ flag,
                                                 const void* __restrict__ drug_emb,
                                                 const void* __restrict__ Wf1,
                                                 float* __restrict__ Dc) {
    if (*flag != (int)F32) return;
    int d = blockIdx.x;  // 0..255
    __shared__ float x[DRUG_EMB];
    __shared__ float red[4];
    if (threadIdx.x < DRUG_EMB) x[threadIdx.x] = ld<F32>(drug_emb, d * DRUG_EMB + threadIdx.x);
    __syncthreads();
    float ss = 0.f;
    if (threadIdx.x < DRUG_EMB) ss = x[threadIdx.x] * x[threadIdx.x];
    for (int o = 32; o > 0; o >>= 1) ss += __shfl_down(ss, o, 64);
    if ((threadIdx.x & 63) == 0) red[threadIdx.x >> 6] = ss;
    __syncthreads();
    float inv = 1.f / fmaxf(sqrtf(red[0] + red[1] + red[2] + red[3]), 1e-12f);
    int j = threadIdx.x;
    if (j < HID) {
        float acc = 0.f;
        for (int k = 0; k < DRUG_EMB; ++k)
            acc = fmaf(x[k], ld<F32>(Wf1, (CELL_EMB + k) * HID + j), acc);
        Dc[d * HID + j] = acc * inv;
    }
}

// ---------------- fused per-sample MLP
template <bool F32>
__global__ __launch_bounds__(256) void main_kernel(const int* __restrict__ flag,
                                                   const int* __restrict__ idx,
                                                   const int* __restrict__ tidx,
                                                   const int* __restrict__ is_missing,
                                                   const int* __restrict__ cell_map,
                                                   const int* __restrict__ drug_map,
                                                   const float* __restrict__ Cc,
                                                   const float* __restrict__ Dc,
                                                   const void* __restrict__ bf1,
                                                   const void* __restrict__ Wf2,
                                                   const void* __restrict__ bf2,
                                                   const void* __restrict__ Wf3,
                                                   const void* __restrict__ bf3,
                                                   void* __restrict__ out, int nB) {
    if (*flag != (int)F32) return;
    __shared__ float h1t[HID][S];   // [i][s]: s contiguous for broadcast-friendly reads
    __shared__ float h2[S][HID];
    __shared__ float wf3s[HID * NDOSES];
    __shared__ float bf3s[NDOSES];
    __shared__ int keyc[S], keyd[S];
    __shared__ float fwds[S][NDOSES];

    int b0 = blockIdx.x * S;
    int tid = threadIdx.x;

    if (tid < S) {
        int b = b0 + tid;
        if (b < nB) {
            int i = idx[b];
            int cm = cell_map[i];
            keyc[tid] = (is_missing[i] != 0) ? (N_MISSING + cm) : cm;
            keyd[tid] = drug_map[tidx[b]];
        } else {
            keyc[tid] = 0; keyd[tid] = 0;   // padded lanes: compute garbage, never stored
        }
    }
    for (int t = tid; t < HID * NDOSES; t += 256) wf3s[t] = ld<F32>(Wf3, t);
    if (tid < NDOSES) bf3s[tid] = ld<F32>(bf3, tid);
    __syncthreads();

    // h1 = relu(Cc[keyc] + Dc[keyd] + bf1)
    for (int t = tid; t < S * HID; t += 256) {
        int s = t / HID;
        int j = t - s * HID;
        float v = Cc[keyc[s] * HID + j] + Dc[keyd[s] * HID + j] + ld<F32>(bf1, j);
        h1t[j][s] = fmaxf(v, 0.f);
    }
    __syncthreads();

    // h2 = relu(h1 @ Wf2 + bf2); thread j streams column j of Wf2 for all S samples
    if (tid < HID) {
        float acc[S];
#pragma unroll
        for (int s = 0; s < S; ++s) acc[s] = 0.f;
        for (int i = 0; i < HID; ++i) {
            float w = ld<F32>(Wf2, i * HID + tid);
#pragma unroll
            for (int s = 0; s < S; ++s) acc[s] = fmaf(h1t[i][s], w, acc[s]);
        }
        float bb = ld<F32>(bf2, tid);
#pragma unroll
        for (int s = 0; s < S; ++s) h2[s][tid] = fmaxf(acc[s] + bb, 0.f);
    }
    __syncthreads();

    // fwd = h2 @ Wf3 + bf3
    if (tid < S * NDOSES) {
        int s = tid / NDOSES;
        int k = tid - s * NDOSES;
        float acc = bf3s[k];
        for (int j = 0; j < HID; ++j)
            acc = fmaf(h2[s][j], wf3s[j * NDOSES + k], acc);
        fwds[s][k] = acc;
    }
    __syncthreads();

    // mu = [fwd0, fwd0 + cumsum(softplus(fwd[1:]))]
    if (tid < S && b0 + tid < nB) {
        float m = fwds[tid][0];
        long o = (long)(b0 + tid) * NDOSES;
        if (F32) ((float*)out)[o] = m; else ((bf16*)out)[o] = __float2bfloat16(m);
#pragma unroll
        for (int k = 1; k < NDOSES; ++k) {
            float x = fwds[tid][k];
            float sp = (x > 20.f) ? x : log1pf(expf(x));
            m += sp;
            if (F32) ((float*)out)[o + k] = m;
            else     ((bf16*)out)[o + k] = __float2bfloat16(m);
        }
    }
}

extern "C" void kernel_launch(void* const* d_in, const int* in_sizes, int n_in,
                              void* d_out, int out_size, void* d_ws, size_t ws_size,
                              hipStream_t stream) {
    const int* idx        = (const int*)d_in[0];
    const int* tidx       = (const int*)d_in[1];
    const int* is_missing = (const int*)d_in[2];
    const int* cell_map   = (const int*)d_in[3];
    const int* drug_map   = (const int*)d_in[4];
    const void* cell_features = d_in[5];
    const void* missing_emb   = d_in[6];
    const void* drug_emb      = d_in[7];
    const void* W1   = d_in[8];
    const void* b1   = d_in[9];
    const void* Wf1  = d_in[10];
    const void* bf1v = d_in[11];
    const void* Wf2  = d_in[12];
    const void* bf2v = d_in[13];
    const void* Wf3  = d_in[14];
    const void* bf3v = d_in[15];

    int nB = in_sizes[0];

    float* ws   = (float*)d_ws;
    int*   flag = (int*)d_ws;            // ws[0]
    float* P    = ws + 64;               // 100*1024 = 102400 floats
    float* Cc   = P + 102400;            // 200*200  = 40000 floats
    float* Dc   = Cc + 40000;            // 256*200  = 51200 floats
                                         // total ~194k floats = 775 KB

    hipLaunchKernelGGL(sniff_kernel, dim3(1), dim3(64), 0, stream,
                       (const unsigned short*)W1, flag);

#define LAUNCH_BOTH(name, grid, blk, ...)                                          \
    hipLaunchKernelGGL((name<false>), grid, blk, 0, stream, flag, __VA_ARGS__);    \
    hipLaunchKernelGGL((name<true>),  grid, blk, 0, stream, flag, __VA_ARGS__);

    LAUNCH_BOTH(present_kernel, dim3(N_MISSING, 4), dim3(256),
                cell_features, W1, b1, P)
    LAUNCH_BOTH(cc_kernel, dim3(2 * N_MISSING), dim3(256),
                P, missing_emb, Wf1, Cc)
    LAUNCH_BOTH(dc_kernel, dim3(N_DRUGS), dim3(256),
                drug_emb, Wf1, Dc)
    LAUNCH_BOTH(main_kernel, dim3((nB + S - 1) / S), dim3(256),
                idx, tidx, is_missing, cell_map, drug_map, Cc, Dc,
                bf1v, Wf2, bf2v, Wf3, bf3v, d_out, nB)
#undef LAUNCH_BOTH
}

// Round 3
// 261.154 us; speedup vs baseline: 1.3242x; 1.3242x over previous
//
#include <hip/hip_runtime.h>
#include <hip/hip_bf16.h>

#define NFEAT 1024
#define CELL_EMB 1024
#define DRUG_EMB 128
#define HID 200
#define NDOSES 9
#define N_MISSING 100
#define N_DRUGS 256
#define S 16

typedef __hip_bfloat16 bf16;
typedef __attribute__((ext_vector_type(8))) short short8;
typedef __attribute__((ext_vector_type(4))) float float4v;

__device__ __forceinline__ float bf2f(short s) {
    unsigned u = ((unsigned)(unsigned short)s) << 16;
    return __builtin_bit_cast(float, u);
}
__device__ __forceinline__ short f2bf(float f) {
    unsigned u = __builtin_bit_cast(unsigned, f);
    unsigned r = (u + 0x7FFFu + ((u >> 16) & 1u)) >> 16;
    return (short)r;
}
template <bool F32>
__device__ __forceinline__ float ld(const void* p, int i) {
    if (F32) return ((const float*)p)[i];
    return bf2f(((const short*)p)[i]);
}
__device__ __forceinline__ float ldr(const void* p, int i, bool f32) {
    return f32 ? ((const float*)p)[i] : bf2f(((const short*)p)[i]);
}
__device__ __forceinline__ float softplusf(float x) {
    return (x > 20.f) ? x : log1pf(expf(x));
}

// ============================ NEW FAST PATH ============================

// dtype sniff: real bf16 W1 (sigma 0.02) never has |x|>=8 (exp>=130); fp32 read
// as bf16 has random exponent bits in even halfwords -> triggers.
__global__ void sniff_k(const unsigned short* __restrict__ w, int* __restrict__ flag) {
    __shared__ int sf;
    if (threadIdx.x == 0) sf = 0;
    __syncthreads();
    int f = 0;
    for (int i = threadIdx.x; i < 4096; i += 256) {
        unsigned e = (w[i] >> 7) & 0xFFu;
        if (e >= 130u) f = 1;
    }
    if (f) atomicOr(&sf, 1);
    __syncthreads();
    if (threadIdx.x == 0) *flag = sf;
}

template <bool F32>
__device__ float dotW1(const float* feat, const void* W1, int j) {
    float acc = 0.f;
#pragma unroll 8
    for (int k = 0; k < NFEAT; ++k)
        acc = fmaf(feat[k], ld<F32>(W1, k * CELL_EMB + j), acc);
    return acc;
}

// P[c] = relu(CF[c] @ W1 + b1), c<100
__global__ __launch_bounds__(256) void present_k(const int* __restrict__ flag,
                                                 const void* __restrict__ CF,
                                                 const void* __restrict__ W1,
                                                 const void* __restrict__ b1,
                                                 float* __restrict__ P) {
    __shared__ float feat[NFEAT];
    bool f32 = (*flag != 0);
    int c = blockIdx.x, jb = blockIdx.y, tid = threadIdx.x;
    for (int k = tid; k < NFEAT; k += 256) feat[k] = ldr(CF, c * NFEAT + k, f32);
    __syncthreads();
    int j = jb * 256 + tid;
    float acc = ldr(b1, j, f32);
    acc += f32 ? dotW1<true>(feat, W1, j) : dotW1<false>(feat, W1, j);
    P[c * CELL_EMB + j] = fmaxf(acc, 0.f);
}

// invC[r] = 1/max(||X_r||, eps), X_r = r<100 ? P[r] : missing_emb[r-100]
__global__ __launch_bounds__(256) void normc_k(const int* __restrict__ flag,
                                               const float* __restrict__ P,
                                               const void* __restrict__ missing_emb,
                                               float* __restrict__ invC) {
    bool f32 = (*flag != 0);
    int r = blockIdx.x, tid = threadIdx.x;
    __shared__ float red[4];
    float ss = 0.f;
    if (r < N_MISSING) {
        for (int k = tid; k < CELL_EMB; k += 256) { float x = P[r * CELL_EMB + k]; ss += x * x; }
    } else {
        for (int k = tid; k < CELL_EMB; k += 256) {
            float x = ldr(missing_emb, (r - N_MISSING) * CELL_EMB + k, f32); ss += x * x;
        }
    }
    for (int o = 32; o > 0; o >>= 1) ss += __shfl_down(ss, o, 64);
    if ((tid & 63) == 0) red[tid >> 6] = ss;
    __syncthreads();
    if (tid == 0)
        invC[r] = 1.f / fmaxf(sqrtf(red[0] + red[1] + red[2] + red[3]), 1e-12f);
}

template <bool F32>
__device__ float dotWf1c(const float* x, const void* Wf1, int base, int j) {
    float acc = 0.f;
#pragma unroll 8
    for (int t = 0; t < 256; ++t)
        acc = fmaf(x[t], ld<F32>(Wf1, (base + t) * HID + j), acc);
    return acc;
}

// Cc_un[r][j] += X_r[kchunk] @ Wf1[kchunk][j]  (unnormalized; invC applied later)
__global__ __launch_bounds__(256) void cc_k(const int* __restrict__ flag,
                                            const float* __restrict__ P,
                                            const void* __restrict__ missing_emb,
                                            const void* __restrict__ Wf1,
                                            float* __restrict__ Cc) {
    __shared__ float x[256];
    bool f32 = (*flag != 0);
    int r = blockIdx.x, kc = blockIdx.y, tid = threadIdx.x;
    int k = kc * 256 + tid;
    x[tid] = (r < N_MISSING) ? P[r * CELL_EMB + k]
                             : ldr(missing_emb, (r - N_MISSING) * CELL_EMB + k, f32);
    __syncthreads();
    if (tid < HID) {
        float acc = f32 ? dotWf1c<true>(x, Wf1, kc * 256, tid)
                        : dotWf1c<false>(x, Wf1, kc * 256, tid);
        atomicAdd(&Cc[r * HID + tid], acc);
    }
}

template <bool F32>
__device__ float dotWf1d(const float* x, const void* Wf1, int j) {
    float acc = 0.f;
#pragma unroll 8
    for (int t = 0; t < DRUG_EMB; ++t)
        acc = fmaf(x[t], ld<F32>(Wf1, (CELL_EMB + t) * HID + j), acc);
    return acc;
}

// Dc[d] = l2norm(drug_emb[d]) @ Wf1[1024:]
__global__ __launch_bounds__(256) void dc_k(const int* __restrict__ flag,
                                            const void* __restrict__ drug_emb,
                                            const void* __restrict__ Wf1,
                                            float* __restrict__ Dc) {
    bool f32 = (*flag != 0);
    int d = blockIdx.x, tid = threadIdx.x;
    __shared__ float x[DRUG_EMB];
    __shared__ float red[4];
    if (tid < DRUG_EMB) x[tid] = ldr(drug_emb, d * DRUG_EMB + tid, f32);
    __syncthreads();
    float ss = 0.f;
    if (tid < DRUG_EMB) ss = x[tid] * x[tid];
    for (int o = 32; o > 0; o >>= 1) ss += __shfl_down(ss, o, 64);
    if ((tid & 63) == 0) red[tid >> 6] = ss;
    __syncthreads();
    float inv = 1.f / fmaxf(sqrtf(red[0] + red[1] + red[2] + red[3]), 1e-12f);
    if (tid < HID) {
        float acc = f32 ? dotWf1d<true>(x, Wf1, tid) : dotWf1d<false>(x, Wf1, tid);
        Dc[d * HID + tid] = acc * inv;
    }
}

// ---- pair MFMA kernel: mu[c*256+d][0..9) for all 51200 pairs ----
// Block = 128 pair rows (one c, 128 consecutive d). K=200 pad 224 (7 steps of 32).
// N=200 pad 224, split into 2 passes of 7 n-tiles (LDS budget 64 KB).
// A/B staged in LDS in MFMA fragment order -> conflict-free ds_read_b128.
#define KP 224
#define KSTEPS 7
#define NTP 7
#define MB 128

__global__ __launch_bounds__(256) void pair_k(const int* __restrict__ flag,
                                              const float* __restrict__ Cc,
                                              const float* __restrict__ Dc,
                                              const float* __restrict__ invC,
                                              const void* __restrict__ bf1,
                                              const void* __restrict__ Wf2,
                                              const void* __restrict__ bf2,
                                              const void* __restrict__ Wf3,
                                              float* __restrict__ mu) {
    __shared__ short8 Bf[NTP * KSTEPS * 64];  // 50176 B
    __shared__ short8 Af[8 * 64];             // 8192 B
    __shared__ float Crow[KP];                // Cc[c]*invC + bf1 (fp32)
    __shared__ float bf2s[KP];
    __shared__ short wf3s[KP * NDOSES];       // bf16
    bool f32 = (*flag != 0);
    int tid = threadIdx.x;
    int lane = tid & 63, w = tid >> 6;
    int q = lane >> 4, col = lane & 15;
    int r0 = blockIdx.x * MB;
    int c = r0 >> 8;
    int d0 = r0 & 255;

    float ic = invC[c];
    for (int k = tid; k < KP; k += 256) {
        Crow[k] = (k < HID) ? Cc[c * HID + k] * ic + ldr(bf1, k, f32) : 0.f;
        bf2s[k] = (k < HID) ? ldr(bf2, k, f32) : 0.f;
    }
    for (int t = tid; t < KP * NDOSES; t += 256) {
        int k = t / NDOSES, dd = t - k * NDOSES;
        wf3s[t] = (k < HID) ? f2bf(ldr(Wf3, k * NDOSES + dd, f32)) : (short)0;
    }

    float fw[8][9];
#pragma unroll
    for (int i = 0; i < 8; ++i)
#pragma unroll
        for (int dd = 0; dd < 9; ++dd) fw[i][dd] = 0.f;

    for (int p = 0; p < 2; ++p) {
        __syncthreads();
        // stage B fragments for this pass: n in [112p, 112p+112)
        for (int t = tid; t < NTP * KSTEPS * 64; t += 256) {
            int chunk = t >> 6, l = t & 63;
            int nt = chunk / KSTEPS, ks = chunk - nt * KSTEPS;
            int n = p * 112 + nt * 16 + (l & 15);
            int k0 = ks * 32 + (l >> 4) * 8;
            short8 v;
#pragma unroll
            for (int j = 0; j < 8; ++j) {
                int k = k0 + j;
                float xv = (k < HID && n < HID) ? ldr(Wf2, k * HID + n, f32) : 0.f;
                v[j] = f2bf(xv);
            }
            Bf[t] = v;
        }
        float4v acc0[7], acc1[7];
#pragma unroll
        for (int nt = 0; nt < 7; ++nt) { acc0[nt] = 0.f; acc1[nt] = 0.f; }

        for (int s = 0; s < KSTEPS; ++s) {
            __syncthreads();
            // build A (h1) slice s in fragment order
            for (int t = tid; t < 8 * 64; t += 256) {
                int mt = t >> 6, l = t & 63;
                int row = mt * 16 + (l & 15);
                int k0 = s * 32 + (l >> 4) * 8;
                short8 v;
                if (k0 < HID) {  // k0 multiple of 8, HID=200 -> k0+7 <= 199
                    const float* dp = Dc + (d0 + row) * HID + k0;
#pragma unroll
                    for (int j = 0; j < 8; ++j) {
                        float xv = Crow[k0 + j] + dp[j];
                        v[j] = f2bf(fmaxf(xv, 0.f));
                    }
                } else {
#pragma unroll
                    for (int j = 0; j < 8; ++j) v[j] = 0;
                }
                Af[t] = v;
            }
            __syncthreads();
            short8 a0 = Af[(2 * w + 0) * 64 + lane];
            short8 a1 = Af[(2 * w + 1) * 64 + lane];
#pragma unroll
            for (int nt = 0; nt < 7; ++nt) {
                short8 bb = Bf[(nt * KSTEPS + s) * 64 + lane];
                acc0[nt] = __builtin_amdgcn_mfma_f32_16x16x32_bf16(a0, bb, acc0[nt], 0, 0, 0);
                acc1[nt] = __builtin_amdgcn_mfma_f32_16x16x32_bf16(a1, bb, acc1[nt], 0, 0, 0);
            }
        }
        // epilogue contribution: h2=relu(acc+bf2); fw[row][dose] += h2*Wf3[n][dose]
#pragma unroll
        for (int nt = 0; nt < 7; ++nt) {
            int n = p * 112 + nt * 16 + col;
            float bb2 = bf2s[n];
            float w3[9];
#pragma unroll
            for (int dd = 0; dd < 9; ++dd) w3[dd] = bf2f(wf3s[n * NDOSES + dd]);
#pragma unroll
            for (int mt = 0; mt < 2; ++mt)
#pragma unroll
                for (int rg = 0; rg < 4; ++rg) {
                    float h2 = fmaxf((mt ? acc1[nt][rg] : acc0[nt][rg]) + bb2, 0.f);
#pragma unroll
                    for (int dd = 0; dd < 9; ++dd)
                        fw[mt * 4 + rg][dd] = fmaf(h2, w3[dd], fw[mt * 4 + rg][dd]);
                }
        }
    }
    // sum over the 16 lanes (n direction) of each quad-group
#pragma unroll
    for (int i = 0; i < 8; ++i)
#pragma unroll
        for (int dd = 0; dd < 9; ++dd) {
            float v = fw[i][dd];
            v += __shfl_xor(v, 1, 16);
            v += __shfl_xor(v, 2, 16);
            v += __shfl_xor(v, 4, 16);
            v += __shfl_xor(v, 8, 16);
            fw[i][dd] = v;
        }
    // softplus + inclusive scan over doses (lane col = dose), store mu rows
#pragma unroll
    for (int i = 0; i < 8; ++i) {
        int mt = i >> 2, rg = i & 3;
        int row = r0 + (2 * w + mt) * 16 + q * 4 + rg;
        float myval = 0.f;
#pragma unroll
        for (int dd = 0; dd < 9; ++dd) myval = (col == dd) ? fw[i][dd] : myval;
        float v = (col == 0) ? myval : softplusf(myval);
        float t1 = __shfl_up(v, 1, 16); if (col >= 1) v += t1;
        float t2 = __shfl_up(v, 2, 16); if (col >= 2) v += t2;
        float t4 = __shfl_up(v, 4, 16); if (col >= 4) v += t4;
        float t8 = __shfl_up(v, 8, 16); if (col >= 8) v += t8;
        if (col < NDOSES) mu[row * NDOSES + col] = v;
    }
}

// final gather: out[b] = mu[keyc(b)*256 + keyd(b)]
__global__ __launch_bounds__(256) void gather_k(const int* __restrict__ flag,
                                                const int* __restrict__ idx,
                                                const int* __restrict__ tidx,
                                                const int* __restrict__ is_missing,
                                                const int* __restrict__ cell_map,
                                                const int* __restrict__ drug_map,
                                                const float* __restrict__ mu,
                                                void* __restrict__ out, int nB) {
    int b = blockIdx.x * 256 + threadIdx.x;
    if (b >= nB) return;
    bool f32 = (*flag != 0);
    int i = idx[b];
    int cm = cell_map[i];
    int kc = (is_missing[i] != 0) ? (N_MISSING + cm) : cm;
    int kd = drug_map[tidx[b]];
    const float* mr = mu + (size_t)(kc * 256 + kd) * NDOSES;
    if (f32) {
        float* o = (float*)out + (size_t)b * NDOSES;
#pragma unroll
        for (int dd = 0; dd < 9; ++dd) o[dd] = mr[dd];
    } else {
        short* o = (short*)out + (size_t)b * NDOSES;
#pragma unroll
        for (int dd = 0; dd < 9; ++dd) o[dd] = f2bf(mr[dd]);
    }
}

// ============================ FALLBACK (Round-2, proven) ============================

__global__ void sniff_kernel(const unsigned short* __restrict__ w1bits, int* __restrict__ flag) {
    if (threadIdx.x == 0 && blockIdx.x == 0) {
        int f = 0;
        for (int i = 0; i < 512; ++i) {
            unsigned int e = (w1bits[i] >> 7) & 0xFFu;
            if (e >= 130u) f = 1;
        }
        *flag = f;
    }
}

template <bool F32>
__global__ __launch_bounds__(256) void present_kernel(const int* __restrict__ flag,
                                                      const void* __restrict__ cell_features,
                                                      const void* __restrict__ W1,
                                                      const void* __restrict__ b1,
                                                      float* __restrict__ P) {
    if (*flag != (int)F32) return;
    __shared__ float feat[NFEAT];
    int c = blockIdx.x, jb = blockIdx.y;
    for (int k = threadIdx.x; k < NFEAT; k += 256)
        feat[k] = ld<F32>(cell_features, c * NFEAT + k);
    __syncthreads();
    int j = jb * 256 + threadIdx.x;
    float acc = ld<F32>(b1, j);
    for (int k = 0; k < NFEAT; ++k)
        acc = fmaf(feat[k], ld<F32>(W1, k * CELL_EMB + j), acc);
    P[c * CELL_EMB + j] = fmaxf(acc, 0.f);
}

template <bool F32>
__global__ __launch_bounds__(256) void cc_kernel(const int* __restrict__ flag,
                                                 const float* __restrict__ P,
                                                 const void* __restrict__ missing_emb,
                                                 const void* __restrict__ Wf1,
                                                 float* __restrict__ Cc) {
    if (*flag != (int)F32) return;
    int r = blockIdx.x;
    __shared__ float x[CELL_EMB];
    __shared__ float red[4];
    if (r < N_MISSING) {
        for (int k = threadIdx.x; k < CELL_EMB; k += 256) x[k] = P[r * CELL_EMB + k];
    } else {
        for (int k = threadIdx.x; k < CELL_EMB; k += 256)
            x[k] = ld<F32>(missing_emb, (r - N_MISSING) * CELL_EMB + k);
    }
    __syncthreads();
    float ss = 0.f;
    for (int k = threadIdx.x; k < CELL_EMB; k += 256) ss += x[k] * x[k];
    for (int o = 32; o > 0; o >>= 1) ss += __shfl_down(ss, o, 64);
    if ((threadIdx.x & 63) == 0) red[threadIdx.x >> 6] = ss;
    __syncthreads();
    float inv = 1.f / fmaxf(sqrtf(red[0] + red[1] + red[2] + red[3]), 1e-12f);
    int j = threadIdx.x;
    if (j < HID) {
        float acc = 0.f;
        for (int k = 0; k < CELL_EMB; ++k)
            acc = fmaf(x[k], ld<F32>(Wf1, k * HID + j), acc);
        Cc[r * HID + j] = acc * inv;
    }
}

template <bool F32>
__global__ __launch_bounds__(256) void dc_kernel(const int* __restrict__ flag,
                                                 const void* __restrict__ drug_emb,
                                                 const void* __restrict__ Wf1,
                                                 float* __restrict__ Dc) {
    if (*flag != (int)F32) return;
    int d = blockIdx.x;
    __shared__ float x[DRUG_EMB];
    __shared__ float red[4];
    if (threadIdx.x < DRUG_EMB) x[threadIdx.x] = ld<F32>(drug_emb, d * DRUG_EMB + threadIdx.x);
    __syncthreads();
    float ss = 0.f;
    if (threadIdx.x < DRUG_EMB) ss = x[threadIdx.x] * x[threadIdx.x];
    for (int o = 32; o > 0; o >>= 1) ss += __shfl_down(ss, o, 64);
    if ((threadIdx.x & 63) == 0) red[threadIdx.x >> 6] = ss;
    __syncthreads();
    float inv = 1.f / fmaxf(sqrtf(red[0] + red[1] + red[2] + red[3]), 1e-12f);
    int j = threadIdx.x;
    if (j < HID) {
        float acc = 0.f;
        for (int k = 0; k < DRUG_EMB; ++k)
            acc = fmaf(x[k], ld<F32>(Wf1, (CELL_EMB + k) * HID + j), acc);
        Dc[d * HID + j] = acc * inv;
    }
}

template <bool F32>
__global__ __launch_bounds__(256) void main_kernel(const int* __restrict__ flag,
                                                   const int* __restrict__ idx,
                                                   const int* __restrict__ tidx,
                                                   const int* __restrict__ is_missing,
                                                   const int* __restrict__ cell_map,
                                                   const int* __restrict__ drug_map,
                                                   const float* __restrict__ Cc,
                                                   const float* __restrict__ Dc,
                                                   const void* __restrict__ bf1,
                                                   const void* __restrict__ Wf2,
                                                   const void* __restrict__ bf2,
                                                   const void* __restrict__ Wf3,
                                                   const void* __restrict__ bf3,
                                                   void* __restrict__ out, int nB) {
    if (*flag != (int)F32) return;
    __shared__ float h1t[HID][S];
    __shared__ float h2[S][HID];
    __shared__ float wf3s[HID * NDOSES];
    __shared__ float bf3s[NDOSES];
    __shared__ int keyc[S], keyd[S];
    __shared__ float fwds[S][NDOSES];

    int b0 = blockIdx.x * S;
    int tid = threadIdx.x;

    if (tid < S) {
        int b = b0 + tid;
        if (b < nB) {
            int i = idx[b];
            int cm = cell_map[i];
            keyc[tid] = (is_missing[i] != 0) ? (N_MISSING + cm) : cm;
            keyd[tid] = drug_map[tidx[b]];
        } else { keyc[tid] = 0; keyd[tid] = 0; }
    }
    for (int t = tid; t < HID * NDOSES; t += 256) wf3s[t] = ld<F32>(Wf3, t);
    if (tid < NDOSES) bf3s[tid] = ld<F32>(bf3, tid);
    __syncthreads();

    for (int t = tid; t < S * HID; t += 256) {
        int s = t / HID;
        int j = t - s * HID;
        float v = Cc[keyc[s] * HID + j] + Dc[keyd[s] * HID + j] + ld<F32>(bf1, j);
        h1t[j][s] = fmaxf(v, 0.f);
    }
    __syncthreads();

    if (tid < HID) {
        float acc[S];
#pragma unroll
        for (int s = 0; s < S; ++s) acc[s] = 0.f;
        for (int i = 0; i < HID; ++i) {
            float wv = ld<F32>(Wf2, i * HID + tid);
#pragma unroll
            for (int s = 0; s < S; ++s) acc[s] = fmaf(h1t[i][s], wv, acc[s]);
        }
        float bb = ld<F32>(bf2, tid);
#pragma unroll
        for (int s = 0; s < S; ++s) h2[s][tid] = fmaxf(acc[s] + bb, 0.f);
    }
    __syncthreads();

    if (tid < S * NDOSES) {
        int s = tid / NDOSES;
        int k = tid - s * NDOSES;
        float acc = bf3s[k];
        for (int j = 0; j < HID; ++j)
            acc = fmaf(h2[s][j], wf3s[j * NDOSES + k], acc);
        fwds[s][k] = acc;
    }
    __syncthreads();

    if (tid < S && b0 + tid < nB) {
        float m = fwds[tid][0];
        long o = (long)(b0 + tid) * NDOSES;
        if (F32) ((float*)out)[o] = m; else ((short*)out)[o] = f2bf(m);
#pragma unroll
        for (int k = 1; k < NDOSES; ++k) {
            float x = fwds[tid][k];
            m += softplusf(x);
            if (F32) ((float*)out)[o + k] = m;
            else     ((short*)out)[o + k] = f2bf(m);
        }
    }
}

// ============================ launcher ============================

extern "C" void kernel_launch(void* const* d_in, const int* in_sizes, int n_in,
                              void* d_out, int out_size, void* d_ws, size_t ws_size,
                              hipStream_t stream) {
    const int* idx        = (const int*)d_in[0];
    const int* tidx       = (const int*)d_in[1];
    const int* is_missing = (const int*)d_in[2];
    const int* cell_map   = (const int*)d_in[3];
    const int* drug_map   = (const int*)d_in[4];
    const void* CF   = d_in[5];
    const void* memb = d_in[6];
    const void* demb = d_in[7];
    const void* W1   = d_in[8];
    const void* b1   = d_in[9];
    const void* Wf1  = d_in[10];
    const void* bf1v = d_in[11];
    const void* Wf2  = d_in[12];
    const void* bf2v = d_in[13];
    const void* Wf3  = d_in[14];
    const void* bf3v = d_in[15];

    int nB = in_sizes[0];
    const size_t NEED = 654720ull * 4ull;  // 2.62 MB

    if (ws_size >= NEED) {
        float* ws   = (float*)d_ws;
        int*   flag = (int*)d_ws;          // [0,64)
        float* invC = ws + 64;             // 256
        float* P    = ws + 320;            // 100*1024
        float* Cc   = ws + 102720;         // 200*200
        float* Dc   = ws + 142720;         // 256*200
        float* mu   = ws + 193920;         // 51200*9

        hipMemsetAsync(Cc, 0, 200 * HID * sizeof(float), stream);
        hipLaunchKernelGGL(sniff_k, dim3(1), dim3(256), 0, stream,
                           (const unsigned short*)W1, flag);
        hipLaunchKernelGGL(present_k, dim3(N_MISSING, 4), dim3(256), 0, stream,
                           flag, CF, W1, b1, P);
        hipLaunchKernelGGL(normc_k, dim3(2 * N_MISSING), dim3(256), 0, stream,
                           flag, P, memb, invC);
        hipLaunchKernelGGL(cc_k, dim3(2 * N_MISSING, 4), dim3(256), 0, stream,
                           flag, P, memb, Wf1, Cc);
        hipLaunchKernelGGL(dc_k, dim3(N_DRUGS), dim3(256), 0, stream,
                           flag, demb, Wf1, Dc);
        hipLaunchKernelGGL(pair_k, dim3(400), dim3(256), 0, stream,
                           flag, Cc, Dc, invC, bf1v, Wf2, bf2v, Wf3, mu);
        hipLaunchKernelGGL(gather_k, dim3((nB + 255) / 256), dim3(256), 0, stream,
                           flag, idx, tidx, is_missing, cell_map, drug_map, mu, d_out, nB);
    } else {
        // Round-2 proven fallback (ws 775 KB)
        float* ws   = (float*)d_ws;
        int*   flag = (int*)d_ws;
        float* P    = ws + 64;
        float* Cc   = P + 102400;
        float* Dc   = Cc + 40000;

        hipLaunchKernelGGL(sniff_kernel, dim3(1), dim3(64), 0, stream,
                           (const unsigned short*)W1, flag);
#define LAUNCH_BOTH(name, grid, blk, ...)                                          \
        hipLaunchKernelGGL((name<false>), grid, blk, 0, stream, flag, __VA_ARGS__);\
        hipLaunchKernelGGL((name<true>),  grid, blk, 0, stream, flag, __VA_ARGS__);
        LAUNCH_BOTH(present_kernel, dim3(N_MISSING, 4), dim3(256), CF, W1, b1, P)
        LAUNCH_BOTH(cc_kernel, dim3(2 * N_MISSING), dim3(256), P, memb, Wf1, Cc)
        LAUNCH_BOTH(dc_kernel, dim3(N_DRUGS), dim3(256), demb, Wf1, Dc)
        LAUNCH_BOTH(main_kernel, dim3((nB + S - 1) / S), dim3(256),
                    idx, tidx, is_missing, cell_map, drug_map, Cc, Dc,
                    bf1v, Wf2, bf2v, Wf3, bf3v, d_out, nB)
#undef LAUNCH_BOTH
    }
}